// Round 7
// baseline (5040.658 us; speedup 1.0000x reference)
//
#include <hip/hip_runtime.h>

// HierarchicalGraphNet: N=100000 nodes, E=320000 edges, D=256, L=3, G=4096.
#define N_NODES 100000
#define N_EDGES 320000
#define N_GRAPH 4096
#define M_PAD   100096                   // N padded to multiple of 128
#define N_TILES 782                      // M_PAD / 128
#define LN_EPS  1e-5f
#define S_EL    ((size_t)M_PAD * 256)    // elements per full M x 256 plane
#define OENC_B  ((size_t)N_GRAPH * 512 * 4)   // m|e encoded maxima

typedef __attribute__((ext_vector_type(8))) short short8;   // 8 x bf16 MFMA operand
typedef __attribute__((ext_vector_type(4))) float f32x4;    // MFMA accumulator
typedef unsigned short u16;

__device__ __forceinline__ float bf2f(u16 u){
  return __uint_as_float(((unsigned)u) << 16);
}
__device__ __forceinline__ u16 f2bf(float f){   // RNE round
  unsigned u = __float_as_uint(f);
  return (u16)((u + 0x7FFFu + ((u >> 16) & 1u)) >> 16);
}
__device__ __forceinline__ unsigned enc_f(float f){
  unsigned u = __float_as_uint(f);
  return (u & 0x80000000u) ? ~u : (u | 0x80000000u);
}
__device__ __forceinline__ float dec_f(unsigned e){
  unsigned u = (e & 0x80000000u) ? (e & 0x7FFFFFFFu) : ~e;
  return __uint_as_float(u);
}
__device__ __forceinline__ float sigm(float x){ return 1.0f/(1.0f + __expf(-x)); }
__device__ __forceinline__ void ld4bf(const u16* p, float* o){
  ushort4 v = *(const ushort4*)p;
  o[0]=bf2f(v.x); o[1]=bf2f(v.y); o[2]=bf2f(v.z); o[3]=bf2f(v.w);
}
// async global->LDS, 16B per lane; LDS dest is wave-uniform base + lane*16.
__device__ __forceinline__ void gl_lds(const u16* g, u16* l){
  __builtin_amdgcn_global_load_lds(
      (const __attribute__((address_space(1))) void*)g,
      (__attribute__((address_space(3))) void*)l, 16, 0, 0);
}

// ---- dtype detector ---------------------------------------------------------
__global__ void k_detect(const unsigned* __restrict__ x32, int* __restrict__ flag){
  unsigned u = x32[threadIdx.x];            // 64 threads
  int ef = (int)((u >> 23) & 0xFFu);
  int ok = (ef >= 64 && ef <= 190) ? 1 : 0;
  #pragma unroll
  for (int o=1; o<64; o<<=1) ok += __shfl_xor(ok, o);
  if (threadIdx.x == 0) *flag = (ok >= 32) ? 1 : 0;
}

// generic external->bf16 converter (or copy when already bf16)
__global__ void k_cvt(const void* __restrict__ src, u16* __restrict__ dst, int n,
                      const int* __restrict__ dflag){
  const bool f32 = (*dflag != 0);
  int base = (blockIdx.x*256 + threadIdx.x) * 4;
  if (base >= n) return;
  if (f32){
    float4 v = *(const float4*)((const float*)src + base);
    *(ushort4*)&dst[base] = make_ushort4(f2bf(v.x), f2bf(v.y), f2bf(v.z), f2bf(v.w));
  } else {
    *(uint2*)&dst[base] = *(const uint2*)((const u16*)src + base);
  }
}

// ---- init kernels -----------------------------------------------------------
__global__ void k_h_init(const void* __restrict__ x, u16* __restrict__ h,
                         const int* __restrict__ dflag){
  const bool f32 = (*dflag != 0);
  int i = blockIdx.x*256 + threadIdx.x;     // 8 elements per thread
  size_t base = (size_t)i*8;
  int n = (int)(base >> 8);
  uint4 v = make_uint4(0,0,0,0);
  if (n < N_NODES){
    if (f32){
      const float* xf = (const float*)x + base;
      float4 a = *(const float4*)xf;
      float4 b = *(const float4*)(xf + 4);
      ushort4 lo = make_ushort4(f2bf(a.x),f2bf(a.y),f2bf(a.z),f2bf(a.w));
      ushort4 hi = make_ushort4(f2bf(b.x),f2bf(b.y),f2bf(b.z),f2bf(b.w));
      v.x = (unsigned)lo.x | ((unsigned)lo.y<<16);
      v.y = (unsigned)lo.z | ((unsigned)lo.w<<16);
      v.z = (unsigned)hi.x | ((unsigned)hi.y<<16);
      v.w = (unsigned)hi.z | ((unsigned)hi.w<<16);
    } else {
      v = *(const uint4*)((const u16*)x + base);
    }
  }
  *(uint4*)&h[base] = v;
}

// aggf = h (fp32; pad rows 0)
__global__ void k_agg_init(const u16* __restrict__ h, float* __restrict__ agg){
  int i = blockIdx.x*256 + threadIdx.x;
  size_t base = (size_t)i*4;
  int n = (int)(base >> 8);
  float4 v = make_float4(0.f,0.f,0.f,0.f);
  if (n < N_NODES){
    ushort4 hv = *(const ushort4*)&h[base];
    v = make_float4(bf2f(hv.x), bf2f(hv.y), bf2f(hv.z), bf2f(hv.w));
  }
  *(float4*)&agg[base] = v;
}

// aggf[dst] += h[src]; one wave per edge, lane covers 4 cols, native f32 atomics
__global__ void k_edge_scatter(const u16* __restrict__ h,
                               const int* __restrict__ ei,
                               float* __restrict__ agg){
  int gid = blockIdx.x*256 + threadIdx.x;
  int e = gid >> 6, lane = gid & 63;
  int s = ei[e], d = ei[N_EDGES + e];
  ushort4 sv = *(const ushort4*)&h[(size_t)s*256 + lane*4];
  float* pp = &agg[(size_t)d*256 + lane*4];
  unsafeAtomicAdd(pp+0, bf2f(sv.x));
  unsafeAtomicAdd(pp+1, bf2f(sv.y));
  unsafeAtomicAdd(pp+2, bf2f(sv.z));
  unsafeAtomicAdd(pp+3, bf2f(sv.w));
}

// ---- GEMM family ------------------------------------------------------------
// C[M,256] = A[M,K] @ B[256,K]^T + bias; all bf16 (MODE 0: A fp32, converted
// while staging). 128x128 tile, BK=32, 4 waves, 4x4 mfma_f32_16x16x32_bf16.
// Staging via global_load_lds width-16 (forced LDS layout base+lane*16);
// k-chunk XOR swizzle (c ^ ((r>>1)&3)) keeps ds_read_b128 at min bank aliasing.
// MODE 0 LIN1 : A fp32, relu            MODE 1 LIN2 : relu
// MODE 2 HN   : none                    MODE 3 RGATE: K=512 dual; sigm * aux
// MODE 4 NGATE: tanh(acc+bias+aux)      MODE 5 ZGATE: K=512 dual; (1-z)*aux+z*hglob
template<int MODE>
__global__ __launch_bounds__(256) void k_gemm(
    const void* __restrict__ A1, const u16* __restrict__ A2,
    const u16* __restrict__ B1, const u16* __restrict__ B2,
    const u16* __restrict__ bias1, const u16* __restrict__ bias2,
    u16* __restrict__ Cout, const u16* __restrict__ aux,
    const u16* __restrict__ hglob)
{
  constexpr int KTOT = (MODE==3 || MODE==5) ? 512 : 256;
  __shared__ u16 As[128*32];
  __shared__ u16 Bs[128*32];
  const int rowBase = blockIdx.x * 128;
  const int colBase = blockIdx.y * 128;
  const int tid  = threadIdx.x;
  const int lane = tid & 63, wave = tid >> 6;
  const int wr = (wave >> 1) * 64, wc = (wave & 1) * 64;
  const int fr = lane & 15, quad = lane >> 4;
  const int sa = (fr >> 1) & 3;              // read-side swizzle component

  f32x4 acc[4][4];
  {
    f32x4 z = {0.f,0.f,0.f,0.f};
    #pragma unroll
    for (int a=0;a<4;a++)
      #pragma unroll
      for (int b=0;b<4;b++) acc[a][b] = z;
  }

  for (int k0 = 0; k0 < KTOT; k0 += 32){
    const u16* Bsrc = (KTOT==512 && k0 >= 256) ? B2 : B1;
    #pragma unroll
    for (int p2=0;p2<2;p2++){
      int id = tid + p2*256;       // 512 tasks: 128 rows x 4 chunks of 8 bf16
      int r  = id >> 2;
      int c  = id & 3;
      int chunk = c ^ ((r >> 1) & 3);
      gl_lds(&Bsrc[(size_t)(colBase + r)*256 + (k0 & 255) + chunk*8], &Bs[id*8]);
      if constexpr (MODE == 0){
        const float* s = &((const float*)A1)[(size_t)(rowBase + r)*256 + k0 + chunk*8];
        float4 a = *(const float4*)s;
        float4 b = *(const float4*)(s + 4);
        *(ushort4*)&As[id*8]     = make_ushort4(f2bf(a.x),f2bf(a.y),f2bf(a.z),f2bf(a.w));
        *(ushort4*)&As[id*8 + 4] = make_ushort4(f2bf(b.x),f2bf(b.y),f2bf(b.z),f2bf(b.w));
      } else {
        const u16* Asrc = (KTOT==512 && k0 >= 256) ? A2 : (const u16*)A1;
        gl_lds(&Asrc[(size_t)(rowBase + r)*256 + (k0 & 255) + chunk*8], &As[id*8]);
      }
    }
    __syncthreads();
    short8 af[4], bfr[4];
    #pragma unroll
    for (int mi=0; mi<4; mi++)
      af[mi] = *(const short8*)&As[(wr + mi*16 + fr)*32 + (quad ^ sa)*8];
    #pragma unroll
    for (int ni=0; ni<4; ni++)
      bfr[ni] = *(const short8*)&Bs[(wc + ni*16 + fr)*32 + (quad ^ sa)*8];
    #pragma unroll
    for (int mi=0; mi<4; mi++)
      #pragma unroll
      for (int ni=0; ni<4; ni++)
        acc[mi][ni] = __builtin_amdgcn_mfma_f32_16x16x32_bf16(af[mi], bfr[ni], acc[mi][ni], 0, 0, 0);
    __syncthreads();
  }

  #pragma unroll
  for (int mi=0; mi<4; mi++){
    #pragma unroll
    for (int ni=0; ni<4; ni++){
      const int col = colBase + wc + ni*16 + fr;      // C/D: col = lane&15
      float bv = bf2f(bias1[col]);
      if constexpr (MODE==3 || MODE==5) bv += bf2f(bias2[col]);
      #pragma unroll
      for (int r4=0; r4<4; r4++){
        const int row = rowBase + wr + mi*16 + quad*4 + r4;   // row = quad*4+reg
        const size_t idx = (size_t)row*256 + col;
        float v = acc[mi][ni][r4] + bv;
        if constexpr (MODE==0 || MODE==1){
          v = fmaxf(v, 0.f);
        } else if constexpr (MODE==3){
          v = sigm(v) * bf2f(aux[idx]);                 // r * (h@Whn^T + bhh_n)
        } else if constexpr (MODE==4){
          v = tanhf(v + bf2f(aux[idx]));                // n
        } else if constexpr (MODE==5){
          float z = sigm(v);
          v = (1.f - z)*bf2f(aux[idx]) + z*bf2f(hglob[idx]);  // hnew
        }
        Cout[idx] = f2bf(v);
      }
    }
  }
}

// ---- BatchNorm over axis 0 (real N rows only) -------------------------------
__global__ void k_bn_stats(const u16* __restrict__ G, float* __restrict__ sums){
  int col = threadIdx.x;
  int n0 = blockIdx.x * 256;
  int n1 = min(N_NODES, n0 + 256);
  float s1 = 0.f, s2 = 0.f;
  for (int n = n0; n < n1; n++){
    float v = bf2f(G[(size_t)n*256 + col]);
    s1 += v; s2 += v*v;
  }
  unsafeAtomicAdd(&sums[col],       s1);
  unsafeAtomicAdd(&sums[256 + col], s2);
}

__global__ void k_bn_apply(u16* __restrict__ G,
                           const u16* __restrict__ gam, const u16* __restrict__ bet,
                           const float* __restrict__ sums){
  int i = blockIdx.x*256 + threadIdx.x;
  size_t base = (size_t)i*4;
  int col = (int)(base & 255);
  ushort4 v = *(const ushort4*)&G[base];
  float vv[4] = {bf2f(v.x), bf2f(v.y), bf2f(v.z), bf2f(v.w)};
  u16 o[4];
  #pragma unroll
  for (int j=0;j<4;j++){
    float mu  = sums[col+j] * (1.f/N_NODES);
    float var = sums[256+col+j] * (1.f/N_NODES) - mu*mu;
    float sc  = bf2f(gam[col+j]) * rsqrtf(fmaxf(var, 0.f) + LN_EPS);
    o[j] = f2bf((vv[j]-mu)*sc + bf2f(bet[col+j]));
  }
  *(ushort4*)&G[base] = make_ushort4(o[0], o[1], o[2], o[3]);
}

// ---- LayerNorm(hnew) + h/m/e update; layer2: m/e maxima via reduced atomics -
__global__ __launch_bounds__(256) void k_fin(
    const u16* __restrict__ hn, u16* __restrict__ h,
    u16* __restrict__ mb, u16* __restrict__ eb,
    const u16* __restrict__ lng, const u16* __restrict__ lnb,
    const int* __restrict__ batch, unsigned* __restrict__ outenc, int layer)
{
  const int wave = threadIdx.x >> 6, lane = threadIdx.x & 63;
  const int n  = blockIdx.x*4 + wave;
  const int d0 = lane*4;
  const size_t rb = (size_t)n*256 + d0;
  float hv[4], mv[4], ev[4];
  ld4bf(&hn[rb], hv);
  if (layer != 0){ ld4bf(&mb[rb], mv); ld4bf(&eb[rb], ev); }

  float s1 = 0.f, s2 = 0.f;
  #pragma unroll
  for (int j=0;j<4;j++){ s1 += hv[j]; s2 += hv[j]*hv[j]; }
  #pragma unroll
  for (int off=1; off<64; off<<=1){
    s1 += __shfl_xor(s1, off);
    s2 += __shfl_xor(s2, off);
  }
  const float mu   = s1 * (1.f/256.f);
  const float var  = s2 * (1.f/256.f) - mu*mu;
  const float rstd = rsqrtf(fmaxf(var, 0.f) + LN_EPS);

  float hl[4];
  #pragma unroll
  for (int j=0;j<4;j++){
    hl[j] = (hv[j]-mu)*rstd*bf2f(lng[d0+j]) + bf2f(lnb[d0+j]);
    if (layer == 0){ mv[j] = hl[j]; ev[j] = hl[j]; }
    else           { mv[j] *= hl[j]; ev[j] += hl[j]; }
  }
  *(ushort4*)&h[rb]  = make_ushort4(f2bf(hl[0]), f2bf(hl[1]), f2bf(hl[2]), f2bf(hl[3]));
  if (layer != 2){
    *(ushort4*)&mb[rb] = make_ushort4(f2bf(mv[0]), f2bf(mv[1]), f2bf(mv[2]), f2bf(mv[3]));
    *(ushort4*)&eb[rb] = make_ushort4(f2bf(ev[0]), f2bf(ev[1]), f2bf(ev[2]), f2bf(ev[3]));
  } else {
    // block covers 4 rows; pre-reduce m/e across rows when all share one graph.
    __shared__ float redm[1024], rede[1024];
    __shared__ int bgs[4];
    if (lane == 0) bgs[wave] = (n < N_NODES) ? batch[n] : -1;
    #pragma unroll
    for (int j=0;j<4;j++){ redm[wave*256 + d0 + j] = mv[j]; rede[wave*256 + d0 + j] = ev[j]; }
    __syncthreads();
    const bool uniform = (bgs[0] >= 0) && bgs[0]==bgs[1] && bgs[1]==bgs[2] && bgs[2]==bgs[3];
    if (uniform){
      const int c = threadIdx.x;
      float mm = fmaxf(fmaxf(redm[c], redm[256+c]), fmaxf(redm[512+c], redm[768+c]));
      float me = fmaxf(fmaxf(rede[c], rede[256+c]), fmaxf(rede[512+c], rede[768+c]));
      unsigned* ob = &outenc[(size_t)bgs[0]*512];
      atomicMax(&ob[c],       enc_f(mm));
      atomicMax(&ob[256 + c], enc_f(me));
    } else {
      const int bg = (n < N_NODES) ? batch[n] : -1;
      if (bg >= 0){
        unsigned* ob = &outenc[(size_t)bg*512 + d0];
        atomicMax(&ob[0], enc_f(mv[0])); atomicMax(&ob[1], enc_f(mv[1]));
        atomicMax(&ob[2], enc_f(mv[2])); atomicMax(&ob[3], enc_f(mv[3]));
        atomicMax(&ob[256+0], enc_f(ev[0])); atomicMax(&ob[256+1], enc_f(ev[1]));
        atomicMax(&ob[256+2], enc_f(ev[2])); atomicMax(&ob[256+3], enc_f(ev[3]));
      }
    }
  }
}

// ---- atomic-free segment max over sorted batch: h plane -> out slice --------
__global__ __launch_bounds__(256) void k_segmax(
    const u16* __restrict__ plane, void* __restrict__ out, long slice,
    const int* __restrict__ batch, const int* __restrict__ dflag)
{
  const bool f32 = (*dflag != 0);
  const int g = blockIdx.x*4 + (threadIdx.x >> 6);
  const int lane = threadIdx.x & 63;
  int lo = 0, hi = N_NODES;
  while (lo < hi){ int mid = (lo + hi) >> 1; if (batch[mid] < g) lo = mid + 1; else hi = mid; }
  const int s = lo;
  hi = N_NODES;
  while (lo < hi){ int mid = (lo + hi) >> 1; if (batch[mid] < g + 1) lo = mid + 1; else hi = mid; }
  const int epos = lo;

  const float NINF = __uint_as_float(0xFF800000u);
  float a0=NINF, a1=NINF, a2=NINF, a3=NINF;
  for (int r = s; r < epos; r++){
    ushort4 v = *(const ushort4*)&plane[(size_t)r*256 + lane*4];
    a0 = fmaxf(a0, bf2f(v.x)); a1 = fmaxf(a1, bf2f(v.y));
    a2 = fmaxf(a2, bf2f(v.z)); a3 = fmaxf(a3, bf2f(v.w));
  }
  const long ob = (long)g*1280 + slice + lane*4;
  if (f32){
    float* o = (float*)out + ob;
    o[0]=a0; o[1]=a1; o[2]=a2; o[3]=a3;
  } else {
    *(ushort4*)((u16*)out + ob) = make_ushort4(f2bf(a0), f2bf(a1), f2bf(a2), f2bf(a3));
  }
}

// decode m/e maxima: oenc[g*512 + c] -> out[g*1280 + 768 + c]
__global__ void k_decode_me(const unsigned* __restrict__ enc, void* __restrict__ out,
                            const int* __restrict__ dflag){
  const bool f32 = (*dflag != 0);
  int i = blockIdx.x*256 + threadIdx.x;      // 4096*512
  int g = i >> 9, c = i & 511;
  unsigned u = enc[i];
  float f = (u == 0u) ? __uint_as_float(0xFF800000u) : dec_f(u);
  long o = (long)g*1280 + 768 + c;
  if (f32) ((float*)out)[o] = f;
  else     ((u16*)out)[o]   = f2bf(f);
}

// ---- launcher ---------------------------------------------------------------
extern "C" void kernel_launch(void* const* d_in, const int* in_sizes, int n_in,
                              void* d_out, int out_size, void* d_ws, size_t ws_size,
                              hipStream_t stream)
{
  const void* x   = d_in[0];
  const void* l1w = d_in[1];  const void* l1b = d_in[2];
  const void* l2w = d_in[3];  const void* l2b = d_in[4];
  const void* bng = d_in[5];  const void* bnb = d_in[6];
  const void* wih = d_in[7];  const void* whh = d_in[8];
  const void* bih = d_in[9];  const void* bhh = d_in[10];
  const void* lng = d_in[11]; const void* lnb = d_in[12];
  const int* ei    = (const int*)d_in[13];
  const int* batch = (const int*)d_in[14];
  (void)in_sizes; (void)n_in; (void)out_size; (void)ws_size;

  const size_t PL = S_EL * 2;            // bf16 plane bytes (51.25 MB)
  char* p = (char*)d_ws; size_t off = 0;
  auto take = [&](size_t b){ void* q = p + off; off += (b + 255) & ~(size_t)255; return q; };
  u16*      h    = (u16*)take(PL);
  u16*      m    = (u16*)take(PL);
  u16*      e    = (u16*)take(PL);
  u16*      G    = (u16*)take(PL);       // t -> rhn -> hnew
  u16*      S1   = (u16*)take(PL);       // g0/g
  u16*      S2   = (u16*)take(PL);       // hn -> n
  unsigned* oenc = (unsigned*)take(OENC_B);
  u16*      P    = (u16*)take(1581056*2);  // converted bf16 params
  float*    bns  = (float*)take(512*4);
  int*      dflg = (int*)take(256);
  float*    aggf = (float*)S1;           // fp32 agg aliases S1+S2 (dead then)

  // converted-param sub-buffers
  u16* p_l1w = P;              u16* p_l2w = P + 196608;
  u16* p_wih = P + 393216;     u16* p_whh = P + 983040;
  u16* p_l1b = P + 1572864;    u16* p_l2b = P + 1573632;
  u16* p_bih = P + 1574400;    u16* p_bhh = P + 1576704;
  u16* p_bng = P + 1579008;    u16* p_bnb = P + 1579776;
  u16* p_lng = P + 1580544;    u16* p_lnb = P + 1580800;

  k_detect<<<1, 64, 0, stream>>>((const unsigned*)x, dflg);
  hipMemsetAsync(oenc, 0, OENC_B, stream);
  auto cvt = [&](const void* s, u16* d, int n){
    k_cvt<<<(n/4 + 255)/256, 256, 0, stream>>>(s, d, n, dflg);
  };
  cvt(l1w, p_l1w, 196608);  cvt(l2w, p_l2w, 196608);
  cvt(wih, p_wih, 589824);  cvt(whh, p_whh, 589824);
  cvt(l1b, p_l1b, 768);     cvt(l2b, p_l2b, 768);
  cvt(bih, p_bih, 2304);    cvt(bhh, p_bhh, 2304);
  cvt(bng, p_bng, 768);     cvt(bnb, p_bnb, 768);
  cvt(lng, p_lng, 256);     cvt(lnb, p_lnb, 256);
  k_h_init<<<S_EL/8/256, 256, 0, stream>>>(x, h, dflg);

  const dim3 gr1(N_TILES, 2);   // 256-col outputs
  for (int l = 0; l < 3; l++){
    const long wo = (long)l*196608;      // per-layer GRU weight offset (3*256*256)
    const long bo = (long)l*768;
    hipMemsetAsync(bns, 0, 512*4, stream);
    k_agg_init    <<<S_EL/4/256, 256, 0, stream>>>(h, aggf);
    k_edge_scatter<<<(N_EDGES*64)/256, 256, 0, stream>>>(h, ei, aggf);
    // t = relu(agg @ W1^T + b1)
    k_gemm<0><<<gr1, 256, 0, stream>>>(aggf, nullptr, p_l1w + l*65536, nullptr,
                                       p_l1b + l*256, nullptr, G, nullptr, nullptr);
    // g0 = relu(t @ W2^T + b2)
    k_gemm<1><<<gr1, 256, 0, stream>>>(G, nullptr, p_l2w + l*65536, nullptr,
                                       p_l2b + l*256, nullptr, S1, nullptr, nullptr);
    k_bn_stats<<<(N_NODES + 255)/256, 256, 0, stream>>>(S1, bns);
    k_bn_apply<<<S_EL/4/256, 256, 0, stream>>>(S1, p_bng + l*256, p_bnb + l*256, bns);
    // hn = h @ Whn^T + bhh_n
    k_gemm<2><<<gr1, 256, 0, stream>>>(h, nullptr, p_whh + wo + 131072, nullptr,
                                       p_bhh + bo + 512, nullptr, S2, nullptr, nullptr);
    // rhn = sigm([g|h] @ [Wir|Whr]^T + bir + bhr) * hn
    k_gemm<3><<<gr1, 256, 0, stream>>>(S1, h, p_wih + wo, p_whh + wo,
                                       p_bih + bo, p_bhh + bo, G, S2, nullptr);
    // n = tanh(g @ Win^T + bin + rhn)
    k_gemm<4><<<gr1, 256, 0, stream>>>(S1, nullptr, p_wih + wo + 131072, nullptr,
                                       p_bih + bo + 512, nullptr, S2, G, nullptr);
    // hnew = (1-z)*n + z*h
    k_gemm<5><<<gr1, 256, 0, stream>>>(S1, h, p_wih + wo + 65536, p_whh + wo + 65536,
                                       p_bih + bo + 256, p_bhh + bo + 256, G, S2, h);
    k_fin<<<M_PAD/4, 256, 0, stream>>>(G, h, m, e, p_lng, p_lnb, batch, oenc, l);
    k_segmax<<<N_GRAPH/4, 256, 0, stream>>>(h, d_out, (long)l*256, batch, dflg);
  }
  k_decode_me<<<(N_GRAPH*512)/256, 256, 0, stream>>>(oenc, d_out, dflg);
}